// Round 1
// baseline (93.648 us; speedup 1.0000x reference)
//
#include <hip/hip_runtime.h>
#include <math.h>

// RunoffProducingModel: B=512, T=2048, M=N=3, S=3 (all hardcoded in reference).
// One thread per (b,t). All 3x3 state lives in registers; heads and mix-steps
// fully unrolled. Compute-bound on the fp32 VALU (~2k ops/thread).

__global__ __launch_bounds__(256) void runoff_fused(
    const float* __restrict__ rain,
    const float* __restrict__ evap,
    const float* __restrict__ wm,     // (3,3)
    const float* __restrict__ we,     // (3 heads, 3)
    const float* __restrict__ wconv,  // (3 heads, 2, 3)
    const float* __restrict__ w11,    // (3,)
    const float* __restrict__ b11,    // (3,)
    const float* __restrict__ wq,     // (3,3,3)
    const float* __restrict__ wk,     // (3,3,3)
    const float* __restrict__ wv,     // (3,3,3)
    float* __restrict__ out,          // (BT, 3, 3)
    int bt)
{
    const int i = blockIdx.x * blockDim.x + threadIdx.x;
    if (i >= bt) return;

    const float r = rain[i];
    const float e = evap[i];
    const float pn = r * (1.0f / 9.0f);          // r / (N*S)
    const float scale = 0.5773502691896258f;     // 1/sqrt(3)

    float wmv[9];
#pragma unroll
    for (int j = 0; j < 9; ++j) wmv[j] = wm[j];

    float acc[9];

#pragma unroll
    for (int h = 0; h < 3; ++h) {
        // ---- per-head params (uniform addresses -> cached/scalarized) ----
        float weh[3], wc0[3], wc1[3];
#pragma unroll
        for (int n = 0; n < 3; ++n) {
            weh[n] = we[3 * h + n];
            wc0[n] = wconv[6 * h + n];
            wc1[n] = wconv[6 * h + 3 + n];
        }
        const float w11h = w11[h];
        const float b11h = b11[h];
        float wqv[9], wkv[9], wvv[9];
#pragma unroll
        for (int j = 0; j < 9; ++j) {
            wqv[j] = wq[9 * h + j];
            wkv[j] = wk[9 * h + j];
            wvv[j] = wv[9 * h + j];
        }

        float ewe[3], prow[3];
#pragma unroll
        for (int n = 0; n < 3; ++n) { ewe[n] = e * weh[n]; prow[n] = pn + ewe[n]; }

        // x init: ones * wm
        float x[9];
#pragma unroll
        for (int j = 0; j < 9; ++j) x[j] = wmv[j];

#pragma unroll
        for (int s = 0; s < 3; ++s) {
            // y = concat([x, p_row]) + e*we  -> (4,3)
            float y[12];
#pragma unroll
            for (int m = 0; m < 3; ++m)
#pragma unroll
                for (int n = 0; n < 3; ++n) y[3 * m + n] = x[3 * m + n] + ewe[n];
#pragma unroll
            for (int n = 0; n < 3; ++n) y[9 + n] = prow[n];

            // vertical 2xN conv + 1x1 conv
            float v[9];
#pragma unroll
            for (int m = 0; m < 3; ++m)
#pragma unroll
                for (int n = 0; n < 3; ++n) {
                    float t = wc0[n] * y[3 * m + n] + wc1[n] * y[3 * m + 3 + n];
                    v[3 * m + n] = t * w11h + b11h;
                }

            // q = v@wq, k = v@wk, val = v@wv
            float q[9], k[9], val[9];
#pragma unroll
            for (int m = 0; m < 3; ++m)
#pragma unroll
                for (int c = 0; c < 3; ++c) {
                    float aq = 0.f, ak = 0.f, av = 0.f;
#pragma unroll
                    for (int n = 0; n < 3; ++n) {
                        aq += v[3 * m + n] * wqv[3 * n + c];
                        ak += v[3 * m + n] * wkv[3 * n + c];
                        av += v[3 * m + n] * wvv[3 * n + c];
                    }
                    q[3 * m + c] = aq; k[3 * m + c] = ak; val[3 * m + c] = av;
                }

            // a = softmax(q k^T * scale, axis=-1)
            float a[9];
#pragma unroll
            for (int mi = 0; mi < 3; ++mi) {
                float srow[3];
#pragma unroll
                for (int mj = 0; mj < 3; ++mj) {
                    float d = 0.f;
#pragma unroll
                    for (int c = 0; c < 3; ++c) d += q[3 * mi + c] * k[3 * mj + c];
                    srow[mj] = d * scale;
                }
                float mx = fmaxf(srow[0], fmaxf(srow[1], srow[2]));
                float e0 = __expf(srow[0] - mx);
                float e1 = __expf(srow[1] - mx);
                float e2 = __expf(srow[2] - mx);
                float inv = __builtin_amdgcn_rcpf(e0 + e1 + e2);
                a[3 * mi + 0] = e0 * inv;
                a[3 * mi + 1] = e1 * inv;
                a[3 * mi + 2] = e2 * inv;
            }

            // x = a @ val
            float xn[9];
#pragma unroll
            for (int mi = 0; mi < 3; ++mi)
#pragma unroll
                for (int n = 0; n < 3; ++n) {
                    float d = 0.f;
#pragma unroll
                    for (int mj = 0; mj < 3; ++mj) d += a[3 * mi + mj] * val[3 * mj + n];
                    xn[3 * mi + n] = d;
                }
#pragma unroll
            for (int j = 0; j < 9; ++j) x[j] = xn[j];
        }

        // ---- per-head activation + runoff accumulation ----
        // runoff = inf_r * pn - ev_r * e - (swr_new - 1) * wm
        if (h == 0) {
            // swr_new = tanh(x); contribute (1 - tanh)*wm
#pragma unroll
            for (int j = 0; j < 9; ++j) {
                float xc = fminf(fmaxf(x[j], -10.f), 10.f);
                float t = __expf(2.f * xc);
                float th = (t - 1.f) * __builtin_amdgcn_rcpf(t + 1.f);
                acc[j] = (1.f - th) * wmv[j];
            }
        } else {
            // softmax over flattened 9
            float mx = x[0];
#pragma unroll
            for (int j = 1; j < 9; ++j) mx = fmaxf(mx, x[j]);
            float ex[9]; float sum = 0.f;
#pragma unroll
            for (int j = 0; j < 9; ++j) { ex[j] = __expf(x[j] - mx); sum += ex[j]; }
            float inv = __builtin_amdgcn_rcpf(sum);
            if (h == 1) {
#pragma unroll
                for (int j = 0; j < 9; ++j) acc[j] += ex[j] * inv * pn;
            } else {
#pragma unroll
                for (int j = 0; j < 9; ++j) acc[j] -= ex[j] * inv * e;
            }
        }
    }

#pragma unroll
    for (int j = 0; j < 9; ++j) out[9 * i + j] = acc[j];
}

extern "C" void kernel_launch(void* const* d_in, const int* in_sizes, int n_in,
                              void* d_out, int out_size, void* d_ws, size_t ws_size,
                              hipStream_t stream) {
    const float* rain  = (const float*)d_in[0];
    const float* evap  = (const float*)d_in[1];
    const float* wm    = (const float*)d_in[2];
    const float* we    = (const float*)d_in[3];
    const float* wconv = (const float*)d_in[4];
    const float* w11   = (const float*)d_in[5];
    const float* b11   = (const float*)d_in[6];
    const float* wq    = (const float*)d_in[7];
    const float* wk    = (const float*)d_in[8];
    const float* wv    = (const float*)d_in[9];
    float* out = (float*)d_out;

    const int bt = in_sizes[0];  // 512 * 2048
    const int block = 256;
    const int grid = (bt + block - 1) / block;
    hipLaunchKernelGGL(runoff_fused, dim3(grid), dim3(block), 0, stream,
                       rain, evap, wm, we, wconv, w11, b11, wq, wk, wv, out, bt);
}

// Round 2
// 45.638 us; speedup vs baseline: 2.0520x; 2.0520x over previous
//
#include <hip/hip_runtime.h>
#include <math.h>

// RunoffProducingModel: B=512,T=2048, M=N=3,S=3. Pure map over (b,t).
// Round 2: process 2 elements/thread as float2 ext-vectors -> v_pk_*_f32
// (VOP3P, 2x fp32/instr), plus algebraic folding of all weight-only math
// into a 1-thread setup kernel (d_ws), consumed via scalar loads.
//
// ws layout (floats): per head h at 48*h:
//  +0  wc0'[3]   = wconv[h][0]*w11[h]
//  +3  wc1'[3]   = wconv[h][1]*w11[h]
//  +6  sumc[3]   = wc0'+wc1'
//  +9  b11[h]
//  +10 we[h][3]
//  +13 G'[9]     = log2e*(1/sqrt3)*Wq Wk^T   (G'[n][n2] at 13+3n+n2)
//  +22 Wv[9]     (row-major [n][k])
//  +31 A01[6]    = wc0'*wm[m] + wc1'*wm[m+1], m=0,1  (step-0 conv on x=wm)
//  +37 A2[3]     = wc0'*wm[2]
//  global: +144 wm[9], +153 2*wm[9]

typedef float v2 __attribute__((ext_vector_type(2)));

#define LOG2E 1.4426950408889634f
#define SCALE 0.5773502691896258f

static __device__ __forceinline__ v2 sp(float a) { v2 r; r[0] = a; r[1] = a; return r; }
static __device__ __forceinline__ v2 fma2(v2 a, v2 b, v2 c) { return __builtin_elementwise_fma(a, b, c); }
static __device__ __forceinline__ v2 max2(v2 a, v2 b) { return __builtin_elementwise_max(a, b); }

static __device__ __forceinline__ float ex2s(float x) {
#if __has_builtin(__builtin_amdgcn_exp2f)
  return __builtin_amdgcn_exp2f(x);
#else
  return __expf(0.69314718055994531f * x);
#endif
}
static __device__ __forceinline__ v2 ex2v(v2 x) { v2 r; r[0] = ex2s(x[0]); r[1] = ex2s(x[1]); return r; }
static __device__ __forceinline__ v2 rcpv(v2 x) {
  v2 r; r[0] = __builtin_amdgcn_rcpf(x[0]); r[1] = __builtin_amdgcn_rcpf(x[1]); return r;
}

static __device__ __forceinline__ void fold_head(
    int h, const float* wm, const float* we, const float* wconv, const float* w11,
    const float* b11, const float* wq, const float* wk, const float* wv, float* W)
{
  const float w11h = w11[h];
  float wc0[3], wc1[3];
#pragma unroll
  for (int n = 0; n < 3; ++n) {
    wc0[n] = wconv[6 * h + n] * w11h;
    wc1[n] = wconv[6 * h + 3 + n] * w11h;
    W[0 + n] = wc0[n];
    W[3 + n] = wc1[n];
    W[6 + n] = wc0[n] + wc1[n];
    W[10 + n] = we[3 * h + n];
  }
  W[9] = b11[h];
#pragma unroll
  for (int n = 0; n < 3; ++n)
#pragma unroll
    for (int n2 = 0; n2 < 3; ++n2) {
      float d = 0.f;
#pragma unroll
      for (int k = 0; k < 3; ++k) d += wq[9 * h + 3 * n + k] * wk[9 * h + 3 * n2 + k];
      W[13 + 3 * n + n2] = d * (LOG2E * SCALE);
    }
#pragma unroll
  for (int j = 0; j < 9; ++j) W[22 + j] = wv[9 * h + j];
#pragma unroll
  for (int m = 0; m < 2; ++m)
#pragma unroll
    for (int n = 0; n < 3; ++n)
      W[31 + 3 * m + n] = wc0[n] * wm[3 * m + n] + wc1[n] * wm[3 * m + 3 + n];
#pragma unroll
  for (int n = 0; n < 3; ++n) W[37 + n] = wc0[n] * wm[6 + n];
}

__global__ void fold_weights(const float* __restrict__ wm, const float* __restrict__ we,
                             const float* __restrict__ wconv, const float* __restrict__ w11,
                             const float* __restrict__ b11, const float* __restrict__ wq,
                             const float* __restrict__ wk, const float* __restrict__ wv,
                             float* __restrict__ ws)
{
  if (threadIdx.x != 0 || blockIdx.x != 0) return;
  for (int h = 0; h < 3; ++h) fold_head(h, wm, we, wconv, w11, b11, wq, wk, wv, ws + 48 * h);
  for (int j = 0; j < 9; ++j) { ws[144 + j] = wm[j]; ws[153 + j] = 2.f * wm[j]; }
}

template <bool WS>
__global__ __launch_bounds__(256) void runoff_pk(
    const float* __restrict__ rain, const float* __restrict__ evap,
    const float* __restrict__ wsbuf,
    const float* __restrict__ wm, const float* __restrict__ we,
    const float* __restrict__ wconv, const float* __restrict__ w11,
    const float* __restrict__ b11, const float* __restrict__ wq,
    const float* __restrict__ wk, const float* __restrict__ wv,
    float* __restrict__ out, int npair)
{
  const int i = blockIdx.x * blockDim.x + threadIdx.x;
  if (i >= npair) return;

  const v2 r = *reinterpret_cast<const v2*>(rain + 2 * i);
  const v2 e = *reinterpret_cast<const v2*>(evap + 2 * i);
  const v2 pn = r * (1.0f / 9.0f);

  v2 acc[9];

#pragma unroll
  for (int h = 0; h < 3; ++h) {
    float Wl[48];
    const float* W;
    if constexpr (WS) {
      W = wsbuf + 48 * h;
    } else {
      fold_head(h, wm, we, wconv, w11, b11, wq, wk, wv, Wl);
      W = Wl;
    }

    // per-(e,r) conv constants (step-invariant)
    v2 C01[3], C2[3];
#pragma unroll
    for (int n = 0; n < 3; ++n) {
      v2 ewe = e * W[10 + n];
      C01[n] = fma2(sp(W[6 + n]), ewe, sp(W[9]));
      C2[n]  = fma2(sp(W[3 + n]), pn, C01[n]);
    }

    v2 x[9];
#pragma unroll
    for (int s = 0; s < 3; ++s) {
      v2 v[9];
      if (s == 0) {
        // x == wm exactly -> conv folded into A01/A2
#pragma unroll
        for (int n = 0; n < 3; ++n) {
          v[n]     = C01[n] + W[31 + n];
          v[3 + n] = C01[n] + W[34 + n];
          v[6 + n] = C2[n]  + W[37 + n];
        }
      } else {
#pragma unroll
        for (int n = 0; n < 3; ++n) {
          v[n]     = fma2(sp(W[0 + n]), x[n],     fma2(sp(W[3 + n]), x[3 + n], C01[n]));
          v[3 + n] = fma2(sp(W[0 + n]), x[3 + n], fma2(sp(W[3 + n]), x[6 + n], C01[n]));
          v[6 + n] = fma2(sp(W[0 + n]), x[6 + n], C2[n]);
        }
      }

      // u = v*G' (scores in exp2 domain), val = v*Wv
      v2 u[9], val[9];
#pragma unroll
      for (int m = 0; m < 3; ++m)
#pragma unroll
        for (int c = 0; c < 3; ++c) {
          v2 t = v[3 * m + 0] * W[13 + c];
          t = fma2(sp(W[16 + c]), v[3 * m + 1], t);
          t = fma2(sp(W[19 + c]), v[3 * m + 2], t);
          u[3 * m + c] = t;
          v2 tv = v[3 * m + 0] * W[22 + c];
          tv = fma2(sp(W[25 + c]), v[3 * m + 1], tv);
          tv = fma2(sp(W[28 + c]), v[3 * m + 2], tv);
          val[3 * m + c] = tv;
        }

      // per-row softmax(u_i . v_j) and x_i = a @ val
#pragma unroll
      for (int mi = 0; mi < 3; ++mi) {
        v2 s0 = u[3 * mi] * v[0]; s0 = fma2(u[3 * mi + 1], v[1], s0); s0 = fma2(u[3 * mi + 2], v[2], s0);
        v2 s1 = u[3 * mi] * v[3]; s1 = fma2(u[3 * mi + 1], v[4], s1); s1 = fma2(u[3 * mi + 2], v[5], s1);
        v2 s2 = u[3 * mi] * v[6]; s2 = fma2(u[3 * mi + 1], v[7], s2); s2 = fma2(u[3 * mi + 2], v[8], s2);
        v2 mx = max2(s0, max2(s1, s2));
        v2 e0 = ex2v(s0 - mx), e1 = ex2v(s1 - mx), e2 = ex2v(s2 - mx);
        v2 inv = rcpv(e0 + e1 + e2);
#pragma unroll
        for (int n = 0; n < 3; ++n) {
          v2 t = e2 * val[6 + n];
          t = fma2(e1, val[3 + n], t);
          t = fma2(e0, val[0 + n], t);
          x[3 * mi + n] = inv * t;
        }
      }
    }

    // epilogue: runoff = inf*pn - ev*e + (1 - tanh)*wm
    if (h == 0) {
#pragma unroll
      for (int j = 0; j < 9; ++j) {
        v2 t = ex2v(x[j] * (2.0f * LOG2E));      // exp(2x)
        v2 rc = rcpv(t + 1.0f);                  // (1-tanh(x)) = 2/(exp(2x)+1)
        const float wm2j = WS ? wsbuf[153 + j] : 2.0f * wm[j];
        acc[j] = rc * wm2j;
      }
    } else {
      v2 mx = x[0];
#pragma unroll
      for (int j = 1; j < 9; ++j) mx = max2(mx, x[j]);
      v2 nm = mx * (-LOG2E);
      v2 t[9]; v2 sum = sp(0.f);
#pragma unroll
      for (int j = 0; j < 9; ++j) { t[j] = ex2v(fma2(x[j], sp(LOG2E), nm)); sum = sum + t[j]; }
      v2 inv = rcpv(sum);
      v2 w = (h == 1) ? (inv * pn) : (inv * (sp(0.f) - e));
#pragma unroll
      for (int j = 0; j < 9; ++j) acc[j] = fma2(t[j], w, acc[j]);
    }
  }

  // out[18i .. 18i+17] = [elem0's 9 | elem1's 9]; 8B-aligned float2 stores
  float o[18];
#pragma unroll
  for (int j = 0; j < 9; ++j) { o[j] = acc[j][0]; o[9 + j] = acc[j][1]; }
#pragma unroll
  for (int k = 0; k < 9; ++k) {
    v2 st; st[0] = o[2 * k]; st[1] = o[2 * k + 1];
    *reinterpret_cast<v2*>(out + 18 * i + 2 * k) = st;
  }
}

extern "C" void kernel_launch(void* const* d_in, const int* in_sizes, int n_in,
                              void* d_out, int out_size, void* d_ws, size_t ws_size,
                              hipStream_t stream) {
  const float* rain  = (const float*)d_in[0];
  const float* evap  = (const float*)d_in[1];
  const float* wm    = (const float*)d_in[2];
  const float* we    = (const float*)d_in[3];
  const float* wconv = (const float*)d_in[4];
  const float* w11   = (const float*)d_in[5];
  const float* b11   = (const float*)d_in[6];
  const float* wq    = (const float*)d_in[7];
  const float* wk    = (const float*)d_in[8];
  const float* wv    = (const float*)d_in[9];
  float* out = (float*)d_out;

  const int bt = in_sizes[0];
  const int npair = bt / 2;
  const int block = 256;
  const int grid = (npair + block - 1) / block;

  if (ws_size >= 1024) {
    float* ws = (float*)d_ws;
    hipLaunchKernelGGL(fold_weights, dim3(1), dim3(64), 0, stream,
                       wm, we, wconv, w11, b11, wq, wk, wv, ws);
    hipLaunchKernelGGL((runoff_pk<true>), dim3(grid), dim3(block), 0, stream,
                       rain, evap, (const float*)ws, wm, we, wconv, w11, b11, wq, wk, wv,
                       out, npair);
  } else {
    hipLaunchKernelGGL((runoff_pk<false>), dim3(grid), dim3(block), 0, stream,
                       rain, evap, (const float*)nullptr, wm, we, wconv, w11, b11, wq, wk, wv,
                       out, npair);
  }
}

// Round 3
// 44.381 us; speedup vs baseline: 2.1101x; 1.0283x over previous
//
#include <hip/hip_runtime.h>
#include <math.h>

// RunoffProducingModel: B=512,T=2048, M=N=3,S=3. Pure map over (b,t).
// Round 3: rolled head-loop (L1I-resident ~10KB body), anchored-difference
// softmax (z-formulation, exact max-subtract semantics), packed fp32 (v2),
// weight-only math folded into ws by a 1-thread setup kernel.
//
// ws layout (floats), per head h at 48*h:
//  +0  wc0'[3]    = wconv[h][0]*w11[h]
//  +3  wc1'[3]    = wconv[h][1]*w11[h]
//  +6  sumcwe[3]  = (wc0'+wc1')*we[h][n]
//  +9  b11[h]
//  +13 G'[9]      = log2e/sqrt3 * Wq Wk^T   (G'[n][n2] at 13+3n+n2)
//  +22 Wv[9]      (row-major [n][c])
//  +31 A01[6]     = wc0'*wm[m] + wc1'*wm[m+1], m=0,1   (step-0 conv, x==wm)
//  +37 A2[3]      = wc0'*wm[2]
//  global: +144 wm2[9] = 2*wm

typedef float v2 __attribute__((ext_vector_type(2)));

#define LOG2E 1.4426950408889634f
#define SCALE 0.5773502691896258f

static __device__ __forceinline__ v2 sp(float a) { v2 r; r[0] = a; r[1] = a; return r; }
static __device__ __forceinline__ v2 fma2(v2 a, v2 b, v2 c) { return __builtin_elementwise_fma(a, b, c); }
static __device__ __forceinline__ v2 max2(v2 a, v2 b) { return __builtin_elementwise_max(a, b); }

static __device__ __forceinline__ float ex2s(float x) {
#if __has_builtin(__builtin_amdgcn_exp2f)
  return __builtin_amdgcn_exp2f(x);
#else
  return __expf(0.69314718055994531f * x);
#endif
}
static __device__ __forceinline__ v2 ex2v(v2 x) { v2 r; r[0] = ex2s(x[0]); r[1] = ex2s(x[1]); return r; }
static __device__ __forceinline__ v2 rcpv(v2 x) {
  v2 r; r[0] = __builtin_amdgcn_rcpf(x[0]); r[1] = __builtin_amdgcn_rcpf(x[1]); return r;
}

static __device__ __forceinline__ void fold_head(
    int h, const float* wm, const float* we, const float* wconv, const float* w11,
    const float* b11, const float* wq, const float* wk, const float* wv, float* W)
{
  const float w11h = w11[h];
  float wc0[3], wc1[3];
#pragma unroll
  for (int n = 0; n < 3; ++n) {
    wc0[n] = wconv[6 * h + n] * w11h;
    wc1[n] = wconv[6 * h + 3 + n] * w11h;
    W[0 + n] = wc0[n];
    W[3 + n] = wc1[n];
    W[6 + n] = (wc0[n] + wc1[n]) * we[3 * h + n];
  }
  W[9] = b11[h];
#pragma unroll
  for (int n = 0; n < 3; ++n)
#pragma unroll
    for (int n2 = 0; n2 < 3; ++n2) {
      float d = 0.f;
#pragma unroll
      for (int k = 0; k < 3; ++k) d += wq[9 * h + 3 * n + k] * wk[9 * h + 3 * n2 + k];
      W[13 + 3 * n + n2] = d * (LOG2E * SCALE);
    }
#pragma unroll
  for (int j = 0; j < 9; ++j) W[22 + j] = wv[9 * h + j];
#pragma unroll
  for (int m = 0; m < 2; ++m)
#pragma unroll
    for (int n = 0; n < 3; ++n)
      W[31 + 3 * m + n] = wc0[n] * wm[3 * m + n] + wc1[n] * wm[3 * m + 3 + n];
#pragma unroll
  for (int n = 0; n < 3; ++n) W[37 + n] = wc0[n] * wm[6 + n];
}

__global__ void fold_weights(const float* __restrict__ wm, const float* __restrict__ we,
                             const float* __restrict__ wconv, const float* __restrict__ w11,
                             const float* __restrict__ b11, const float* __restrict__ wq,
                             const float* __restrict__ wk, const float* __restrict__ wv,
                             float* __restrict__ ws)
{
  if (threadIdx.x != 0 || blockIdx.x != 0) return;
  for (int h = 0; h < 3; ++h) fold_head(h, wm, we, wconv, w11, b11, wq, wk, wv, ws + 48 * h);
  for (int j = 0; j < 9; ++j) ws[144 + j] = 2.f * wm[j];
}

template <bool WS>
__global__ __launch_bounds__(256) void runoff3(
    const float* __restrict__ rain, const float* __restrict__ evap,
    const float* __restrict__ wsbuf,
    const float* __restrict__ wm, const float* __restrict__ we,
    const float* __restrict__ wconv, const float* __restrict__ w11,
    const float* __restrict__ b11, const float* __restrict__ wq,
    const float* __restrict__ wk, const float* __restrict__ wv,
    float* __restrict__ out, int npair)
{
  const int i = blockIdx.x * blockDim.x + threadIdx.x;
  if (i >= npair) return;

  const v2 rr = *reinterpret_cast<const v2*>(rain + 2 * i);
  const v2 ee = *reinterpret_cast<const v2*>(evap + 2 * i);
  const v2 pn = rr * (1.0f / 9.0f);

  v2 acc[9];
#pragma unroll
  for (int j = 0; j < 9; ++j) acc[j] = sp(0.f);

#pragma unroll 1
  for (int h = 0; h < 3; ++h) {
    float Wl[48];
    const float* W;
    if constexpr (WS) {
      W = wsbuf + 48 * h;          // uniform address -> scalar (SMEM) loads
    } else {
      fold_head(h, wm, we, wconv, w11, b11, wq, wk, wv, Wl);
      W = Wl;
    }

    // step-invariant per-(e,r) conv constants
    v2 C01[3], C2[3];
#pragma unroll
    for (int n = 0; n < 3; ++n) {
      C01[n] = fma2(ee, sp(W[6 + n]), sp(W[9]));
      C2[n]  = fma2(pn, sp(W[3 + n]), C01[n]);
    }

    v2 x[9];
#pragma unroll
    for (int s = 0; s < 3; ++s) {
      v2 v[9];
      if (s == 0) {
#pragma unroll
        for (int n = 0; n < 3; ++n) {
          v[n]     = C01[n] + W[31 + n];
          v[3 + n] = C01[n] + W[34 + n];
          v[6 + n] = C2[n]  + W[37 + n];
        }
      } else {
#pragma unroll
        for (int n = 0; n < 3; ++n) {
          v[n]     = fma2(sp(W[0 + n]), x[n],     fma2(sp(W[3 + n]), x[3 + n], C01[n]));
          v[3 + n] = fma2(sp(W[0 + n]), x[3 + n], fma2(sp(W[3 + n]), x[6 + n], C01[n]));
          v[6 + n] = fma2(sp(W[0 + n]), x[6 + n], C2[n]);
        }
      }

      // anchored differences: w_j = v_j - v_0 (rows), z_j = G' w_j
      v2 w1[3], w2[3], z1[3], z2[3];
#pragma unroll
      for (int n = 0; n < 3; ++n) { w1[n] = v[3 + n] - v[n]; w2[n] = v[6 + n] - v[n]; }
#pragma unroll
      for (int n = 0; n < 3; ++n) {
        v2 t1 = w1[0] * W[13 + 3 * n];
        t1 = fma2(sp(W[14 + 3 * n]), w1[1], t1);
        t1 = fma2(sp(W[15 + 3 * n]), w1[2], t1);
        z1[n] = t1;
        v2 t2 = w2[0] * W[13 + 3 * n];
        t2 = fma2(sp(W[14 + 3 * n]), w2[1], t2);
        t2 = fma2(sp(W[15 + 3 * n]), w2[2], t2);
        z2[n] = t2;
      }

      // val = v * Wv
      v2 val[9];
#pragma unroll
      for (int m = 0; m < 3; ++m)
#pragma unroll
        for (int c = 0; c < 3; ++c) {
          v2 t = v[3 * m + 0] * W[22 + c];
          t = fma2(sp(W[25 + c]), v[3 * m + 1], t);
          t = fma2(sp(W[28 + c]), v[3 * m + 2], t);
          val[3 * m + c] = t;
        }

      // per-row: d_j = v_i . z_j ; softmax with exact max-subtract via guard 0
#pragma unroll
      for (int mi = 0; mi < 3; ++mi) {
        v2 d1 = v[3 * mi] * z1[0];
        d1 = fma2(v[3 * mi + 1], z1[1], d1);
        d1 = fma2(v[3 * mi + 2], z1[2], d1);
        v2 d2 = v[3 * mi] * z2[0];
        d2 = fma2(v[3 * mi + 1], z2[1], d2);
        d2 = fma2(v[3 * mi + 2], z2[2], d2);
        v2 m = max2(max2(d1, d2), sp(0.f));
        v2 t0 = ex2v(sp(0.f) - m);
        v2 t1 = ex2v(d1 - m);
        v2 t2 = ex2v(d2 - m);
        v2 inv = rcpv(t0 + t1 + t2);
#pragma unroll
        for (int n = 0; n < 3; ++n) {
          v2 u = t0 * val[n];
          u = fma2(t1, val[3 + n], u);
          u = fma2(t2, val[6 + n], u);
          x[3 * mi + n] = u * inv;
        }
      }
    }

    // epilogue: runoff = inf*pn - ev*e + (1 - tanh)*wm
    if (h == 0) {
#pragma unroll
      for (int j = 0; j < 9; ++j) {
        v2 t = ex2v(x[j] * (2.0f * LOG2E));                 // exp(2x)
        const float wm2j = WS ? wsbuf[144 + j] : 2.0f * wm[j];
        acc[j] = acc[j] + rcpv(t + 1.0f) * wm2j;            // 2wm/(exp(2x)+1)
      }
    } else {
      v2 mx = x[0];
#pragma unroll
      for (int j = 1; j < 9; ++j) mx = max2(mx, x[j]);
      v2 nm = mx * (-LOG2E);
      v2 t[9]; v2 sum = sp(0.f);
#pragma unroll
      for (int j = 0; j < 9; ++j) { t[j] = ex2v(fma2(x[j], sp(LOG2E), nm)); sum = sum + t[j]; }
      v2 inv = rcpv(sum);
      v2 wfac = (h == 1) ? (inv * pn) : (sp(0.f) - inv * ee);
#pragma unroll
      for (int j = 0; j < 9; ++j) acc[j] = fma2(t[j], wfac, acc[j]);
    }
  }

  // out[18i .. 18i+17] = [elem0's 9 | elem1's 9]
  float o[18];
#pragma unroll
  for (int j = 0; j < 9; ++j) { o[j] = acc[j][0]; o[9 + j] = acc[j][1]; }
#pragma unroll
  for (int k = 0; k < 9; ++k) {
    v2 st; st[0] = o[2 * k]; st[1] = o[2 * k + 1];
    *reinterpret_cast<v2*>(out + 18 * i + 2 * k) = st;
  }
}

extern "C" void kernel_launch(void* const* d_in, const int* in_sizes, int n_in,
                              void* d_out, int out_size, void* d_ws, size_t ws_size,
                              hipStream_t stream) {
  const float* rain  = (const float*)d_in[0];
  const float* evap  = (const float*)d_in[1];
  const float* wm    = (const float*)d_in[2];
  const float* we    = (const float*)d_in[3];
  const float* wconv = (const float*)d_in[4];
  const float* w11   = (const float*)d_in[5];
  const float* b11   = (const float*)d_in[6];
  const float* wq    = (const float*)d_in[7];
  const float* wk    = (const float*)d_in[8];
  const float* wv    = (const float*)d_in[9];
  float* out = (float*)d_out;

  const int bt = in_sizes[0];
  const int npair = bt / 2;
  const int block = 256;
  const int grid = (npair + block - 1) / block;

  if (ws_size >= 1024) {
    float* ws = (float*)d_ws;
    hipLaunchKernelGGL(fold_weights, dim3(1), dim3(64), 0, stream,
                       wm, we, wconv, w11, b11, wq, wk, wv, ws);
    hipLaunchKernelGGL((runoff3<true>), dim3(grid), dim3(block), 0, stream,
                       rain, evap, (const float*)ws, wm, we, wconv, w11, b11, wq, wk, wv,
                       out, npair);
  } else {
    hipLaunchKernelGGL((runoff3<false>), dim3(grid), dim3(block), 0, stream,
                       rain, evap, (const float*)nullptr, wm, we, wconv, w11, b11, wq, wk, wv,
                       out, npair);
  }
}